// Round 7
// baseline (337.381 us; speedup 1.0000x reference)
//
#include <hip/hip_runtime.h>

// VQ-VAE vector quantizer — R7.
// R6 post-mortem: (a) ~20 us overhead PER LAUNCH (4 launches = ~74 us of the
// 154 us total); (b) VALUBusy implies ~3x my static work estimate -> exact
// rescue fires at ~10-15% of rows (W=0.023 vs E[top-2 gap]~0.15) and its
// serial FMA + scattered loads stall the whole block at the barrier.
// R7: 2 launches (hist+loss+perp fused via done-counter last block);
//     full 4-product bf16x2 MFMA (8/iter) -> sound W halves -> flag rate ~2x down;
//     1-ahead register prefetch of B fragments.

#define B_ 32
#define C_ 64
#define HW_ 4096
#define K_ 512
#define N_ (B_ * HW_)
#define NC_ ((long long)N_ * C_)
#define ROWS_ 64
#define NBLK_ (N_ / ROWS_)     // 2048

typedef __attribute__((ext_vector_type(8))) short short8;
typedef __attribute__((ext_vector_type(4))) float float4_t;

// ---- workspace layout (bytes) ----
// 0       double sse
// 8       int    done
// 56      float  snmax               4*max_k ||e_k||^2
// 2112    float  en[512]
// 4160    float  embT32[512*64]      exact fp32 emb, [code][c]
// 135232  ushort fBhi[512*64]        bf16 hi of (-2e), fragment-linear
// 200768  ushort fBlo[512*64]        bf16 lo of (-2e), fragment-linear
// end     266304

__device__ __forceinline__ unsigned short f2bf(float f) {
    unsigned u = __float_as_uint(f);
    u += 0x7fffu + ((u >> 16) & 1u);   // RNE
    return (unsigned short)(u >> 16);
}
__device__ __forceinline__ float bf2f(unsigned short h) {
    return __uint_as_float(((unsigned)h) << 16);
}
// LDS A-tile (bf16 frag) offset: [row-tile][k-group][row-in-tile][8 k]
__device__ __forceinline__ int offA(int r, int c) {
    return ((r >> 4) << 10) + ((c >> 3) << 7) + ((r & 15) << 3) + (c & 7);
}
__device__ __forceinline__ void merge2(float& m1, int& i1, float& m2,
                                       float om1, int oi1, float om2) {
    if (om1 < m1) { m2 = fminf(m1, om2); m1 = om1; i1 = oi1; }
    else          { m2 = fminf(m2, om1); }
}

// ---------------- prologue ----------------
__global__ __launch_bounds__(512) void vq_init(const float* __restrict__ emb,
                                               double* __restrict__ sse,
                                               int* __restrict__ done,
                                               float* __restrict__ snmax_p,
                                               float* __restrict__ en,
                                               float* __restrict__ embT32,
                                               unsigned short* __restrict__ fBhi,
                                               unsigned short* __restrict__ fBlo) {
    __shared__ float smax[8];
    int k = threadIdx.x;                  // code 0..511
    if (blockIdx.x < 64) {
        int c = blockIdx.x;
        float e = emb[c * K_ + k];        // coalesced over k
        embT32[k * C_ + c] = e;
        float s = -2.0f * e;
        unsigned short hi = f2bf(s);
        unsigned short lo = f2bf(s - bf2f(hi));
        // fragment-linear: fb = [k>>5][(k>>4)&1][c>>5], then lane, then 8 k
        int kk   = c >> 5;
        int lane = (((c & 31) >> 3) << 4) + (k & 15);
        int fb   = ((k >> 5) << 2) + (((k >> 4) & 1) << 1) + kk;
        int off  = (fb << 9) + (lane << 3) + (c & 7);
        fBhi[off] = hi;
        fBlo[off] = lo;
    } else {
        if (k == 0) { *sse = 0.0; *done = 0; }
        float s = 0.f;
#pragma unroll
        for (int c = 0; c < C_; ++c) {
            float e = emb[c * K_ + k];
            s += e * e;
        }
        en[k] = s;
        float m = s;
#pragma unroll
        for (int off = 32; off > 0; off >>= 1)
            m = fmaxf(m, __shfl_down(m, off, 64));
        if ((k & 63) == 0) smax[k >> 6] = m;
        __syncthreads();
        if (k == 0) {
            float mm = smax[0];
#pragma unroll
            for (int w2 = 1; w2 < 8; ++w2) mm = fmaxf(mm, smax[w2]);
            *snmax_p = 4.0f * mm;
        }
    }
}

// ---------------- fused main kernel ----------------
__global__ __launch_bounds__(256) void vq_fused(const float* __restrict__ x,
                                                const float* __restrict__ en_g,
                                                const float* __restrict__ embT32,
                                                const unsigned short* __restrict__ fBhi,
                                                const unsigned short* __restrict__ fBlo,
                                                const float* __restrict__ snmax_p,
                                                float* __restrict__ out_q,
                                                float* __restrict__ out_idx,
                                                float* __restrict__ out_loss,
                                                float* __restrict__ out_perp,
                                                double* __restrict__ sse_g,
                                                int* __restrict__ done) {
    __shared__ unsigned short Ast[ROWS_ * C_];   // 8 KB, reused hi -> lo
    __shared__ float sEn[K_];                    // 2 KB
    __shared__ float znp[4 * ROWS_];             // 1 KB
    __shared__ int   biarr[ROWS_];
    __shared__ int   flaglist[ROWS_];
    __shared__ int   h[K_];                      // 2 KB (last-block histogram)
    __shared__ float wsse[4];
    __shared__ int   nflag;
    __shared__ int   islast;

    const int t   = threadIdx.x;
    const int n0  = blockIdx.x * ROWS_;
    const int b   = n0 >> 12;
    const int hw0 = n0 & 4095;
    const float* xbase = x + ((size_t)b << 18) + hw0;

    if (t == 0) nflag = 0;
    sEn[t]       = en_g[t];
    sEn[256 + t] = en_g[256 + t];

    // ---- stage hi (x retained in regs); thread owns row r=t&63, c = 4i + (t>>6) ----
    float v[16];
    float znacc = 0.f;
#pragma unroll
    for (int i = 0; i < 16; ++i) {
        int id = (i << 8) + t;
        int c = id >> 6;
        int r = id & 63;
        float val = xbase[((size_t)c << 12) + r];   // 256B coalesced
        v[i] = val;
        znacc += val * val;
        Ast[offA(r, c)] = f2bf(val);
    }
    znp[((t >> 6) << 6) + (t & 63)] = znacc;
    __syncthreads();

    const int lane = t & 63;
    const int w    = t >> 6;             // wave owns row-tile w
    const int ln15 = lane & 15;
    const int quad = lane >> 4;
    const float snm = *snmax_p;

    // ---- A-hi frags (16 VGPRs) ----
    const int ab = (w << 10) + (quad << 7) + (ln15 << 3);
    short8 ah0 = *(const short8*)(Ast + ab);
    short8 ah1 = *(const short8*)(Ast + ab + 512);
    __syncthreads();

    // ---- stage lo into same buffer ----
#pragma unroll
    for (int i = 0; i < 16; ++i) {
        int id = (i << 8) + t;
        int c = id >> 6;
        int r = id & 63;
        float val = v[i];
        unsigned short hi = f2bf(val);
        Ast[offA(r, c)] = f2bf(val - bf2f(hi));
    }
    __syncthreads();
    short8 al0 = *(const short8*)(Ast + ab);
    short8 al1 = *(const short8*)(Ast + ab + 512);

    // ---- stream 512 codes: 32 iters x 16 codes; full 4-product; top-2 ----
    float m1[4], m2[4];
    int   i1[4];
#pragma unroll
    for (int reg = 0; reg < 4; ++reg) {
        m1[reg] = 3.4e38f; m2[reg] = 3.4e38f; i1[reg] = 0;
    }

    // 1-ahead register prefetch of B fragments
    short8 nb0 = *(const short8*)(fBhi + (lane << 3));
    short8 nb1 = *(const short8*)(fBhi + (lane << 3) + 512);
    short8 nb2 = *(const short8*)(fBlo + (lane << 3));
    short8 nb3 = *(const short8*)(fBlo + (lane << 3) + 512);

#pragma unroll 2
    for (int it = 0; it < 32; ++it) {
        short8 bh0 = nb0, bh1 = nb1, bl0 = nb2, bl1 = nb3;
        if (it < 31) {
            const int nfb = ((it + 1) << 10) + (lane << 3);
            nb0 = *(const short8*)(fBhi + nfb);
            nb1 = *(const short8*)(fBhi + nfb + 512);
            nb2 = *(const short8*)(fBlo + nfb);
            nb3 = *(const short8*)(fBlo + nfb + 512);
        }
        float env = sEn[(it << 4) + ln15];
        int   idx = (it << 4) + ln15;
        // two independent 4-MFMA chains (k-chunk 0 / 1), full bf16x2 product
        float4_t a0 = {env, env, env, env};   // fold ||e||^2 into acc init
        float4_t a1 = {0.f, 0.f, 0.f, 0.f};
        a0 = __builtin_amdgcn_mfma_f32_16x16x32_bf16(al0, bl0, a0, 0, 0, 0);
        a1 = __builtin_amdgcn_mfma_f32_16x16x32_bf16(al1, bl1, a1, 0, 0, 0);
        a0 = __builtin_amdgcn_mfma_f32_16x16x32_bf16(al0, bh0, a0, 0, 0, 0);
        a1 = __builtin_amdgcn_mfma_f32_16x16x32_bf16(al1, bh1, a1, 0, 0, 0);
        a0 = __builtin_amdgcn_mfma_f32_16x16x32_bf16(ah0, bl0, a0, 0, 0, 0);
        a1 = __builtin_amdgcn_mfma_f32_16x16x32_bf16(ah1, bl1, a1, 0, 0, 0);
        a0 = __builtin_amdgcn_mfma_f32_16x16x32_bf16(ah0, bh0, a0, 0, 0, 0);
        a1 = __builtin_amdgcn_mfma_f32_16x16x32_bf16(ah1, bh1, a1, 0, 0, 0);
#pragma unroll
        for (int reg = 0; reg < 4; ++reg) {
            float vv = a0[reg] + a1[reg];
            if (vv < m1[reg]) {
                m2[reg] = m1[reg]; m1[reg] = vv; i1[reg] = idx;
            } else {
                m2[reg] = fminf(m2[reg], vv);
            }
        }
    }

    // ---- 16-lane butterfly finalize + flag decision ----
#pragma unroll
    for (int reg = 0; reg < 4; ++reg) {
        float a1v = m1[reg], a2v = m2[reg];
        int   ai  = i1[reg];
#pragma unroll
        for (int s = 1; s < 16; s <<= 1) {
            float o1 = __shfl_xor(a1v, s, 16);
            int   oi = __shfl_xor(ai, s, 16);
            float o2 = __shfl_xor(a2v, s, 16);
            merge2(a1v, ai, a2v, o1, oi, o2);
        }
        if (ln15 == 0) {
            int row = (w << 4) + (quad << 2) + reg;
            float znr = znp[row] + znp[64 + row] + znp[128 + row] + znp[192 + row];
            // sound |approx-exact| x2 bound: repr 2*2^-15*S + fp32 accum terms
            float S = __builtin_sqrtf(znr * snm);
            float W = 6.5e-5f * S + 3e-6f * (znr + snm) + 1e-4f;
            biarr[row] = ai;
            if (a2v > a1v + W) {          // gap > W => approx argmin == exact argmin
                __hip_atomic_store(&out_idx[n0 + row], (float)ai,
                                   __ATOMIC_RELAXED, __HIP_MEMORY_SCOPE_AGENT);
            } else {
                int pos = atomicAdd(&nflag, 1);   // LDS atomic
                flaglist[pos] = row;
            }
        }
    }
    __syncthreads();

    // ---- exact fp32 rescue (one wave per flagged row) ----
    int nf = nflag;
    for (int f = w; f < nf; f += 4) {
        int r = flaglist[f];
        float zl = xbase[((size_t)lane << 12) + r];   // exact z[lane], L2-hot
        float d[8];
#pragma unroll
        for (int j = 0; j < 8; ++j) d[j] = 0.f;
        for (int c4 = 0; c4 < 16; ++c4) {
            float z0 = __shfl(zl, (c4 << 2) + 0, 64);
            float z1 = __shfl(zl, (c4 << 2) + 1, 64);
            float z2 = __shfl(zl, (c4 << 2) + 2, 64);
            float z3 = __shfl(zl, (c4 << 2) + 3, 64);
#pragma unroll
            for (int j = 0; j < 8; ++j) {
                float4_t e = *(const float4_t*)(embT32 + ((((lane << 3) + j) << 6) + (c4 << 2)));
                d[j] = fmaf(z0, e[0], d[j]);
                d[j] = fmaf(z1, e[1], d[j]);
                d[j] = fmaf(z2, e[2], d[j]);
                d[j] = fmaf(z3, e[3], d[j]);
            }
        }
        float znr = znp[r] + znp[64 + r] + znp[128 + r] + znp[192 + r];
        float best = 3.4e38f;
        int   bidx = 0;
#pragma unroll
        for (int j = 0; j < 8; ++j) {
            int k = (lane << 3) + j;
            float dist = (znr + sEn[k]) - 2.f * d[j];   // reference eval order
            if (dist < best) { best = dist; bidx = k; }
        }
#pragma unroll
        for (int off = 32; off > 0; off >>= 1) {
            float ov = __shfl_down(best, off, 64);
            int   oi = __shfl_down(bidx, off, 64);
            if (ov < best || (ov == best && oi < bidx)) { best = ov; bidx = oi; }
        }
        if (lane == 0) {
            biarr[r] = bidx;
            __hip_atomic_store(&out_idx[n0 + r], (float)bidx,
                               __ATOMIC_RELAXED, __HIP_MEMORY_SCOPE_AGENT);
        }
    }
    __syncthreads();

    // ---- phase 2 (register-based): lane row = w*16+ln15, c = quad*8+j (+32) ----
    const int myrow = (w << 4) + ln15;
    const int code  = biarr[myrow];
    const float* eb = embT32 + (code << 6) + (quad << 3);
    float4_t e0 = *(const float4_t*)(eb);
    float4_t e1 = *(const float4_t*)(eb + 4);
    float4_t e2 = *(const float4_t*)(eb + 32);
    float4_t e3 = *(const float4_t*)(eb + 36);
    float* qrow = out_q + ((size_t)b << 18) + hw0 + myrow;
    float sacc = 0.f;
#pragma unroll
    for (int j = 0; j < 4; ++j) {
        int c0 = (quad << 3) + j;
        int c1 = (quad << 3) + 4 + j;
        float zA = bf2f((unsigned short)ah0[j])     + bf2f((unsigned short)al0[j]);
        float zB = bf2f((unsigned short)ah0[4 + j]) + bf2f((unsigned short)al0[4 + j]);
        float dA = e0[j] - zA, dB = e1[j] - zB;
        sacc += dA * dA + dB * dB;
        qrow[(size_t)c0 << 12] = e0[j];
        qrow[(size_t)c1 << 12] = e1[j];
        float zC = bf2f((unsigned short)ah1[j])     + bf2f((unsigned short)al1[j]);
        float zD = bf2f((unsigned short)ah1[4 + j]) + bf2f((unsigned short)al1[4 + j]);
        float dC = e2[j] - zC, dD = e3[j] - zD;
        sacc += dC * dC + dD * dD;
        qrow[(size_t)(32 + c0) << 12] = e2[j];
        qrow[(size_t)(32 + c1) << 12] = e3[j];
    }
#pragma unroll
    for (int off = 32; off > 0; off >>= 1)
        sacc += __shfl_down(sacc, off, 64);
    if (lane == 0) wsse[w] = sacc;
    __syncthreads();

    // ---- done counter; last block computes hist + loss + perplexity ----
    if (t == 0) {
        double bs = (double)wsse[0] + (double)wsse[1]
                  + (double)wsse[2] + (double)wsse[3];
        atomicAdd(sse_g, bs);
        __threadfence();
        islast = (atomicAdd(done, 1) == NBLK_ - 1);
    }
    __syncthreads();
    if (islast) {
        __threadfence();
        h[t] = 0; h[t + 256] = 0;
        __syncthreads();
        for (int i = 0; i < N_ / 256; ++i) {
            float fv = __hip_atomic_load(&out_idx[(i << 8) + t],
                                         __ATOMIC_RELAXED, __HIP_MEMORY_SCOPE_AGENT);
            atomicAdd(&h[(int)fv], 1);    // LDS atomic
        }
        __syncthreads();
        float s = 0.f;
#pragma unroll
        for (int j = 0; j < 2; ++j) {
            float pp = (float)h[t + (j << 8)] / (float)N_;
            s += pp * logf(pp + 1e-10f);
        }
#pragma unroll
        for (int off = 32; off > 0; off >>= 1)
            s += __shfl_down(s, off, 64);
        if (lane == 0) wsse[w] = s;
        __syncthreads();
        if (t == 0) {
            float S2 = wsse[0] + wsse[1] + wsse[2] + wsse[3];
            double sv = atomicAdd(sse_g, 0.0);
            out_perp[0] = expf(-S2);
            out_loss[0] = (float)(1.25 * sv / (double)NC_);
        }
    }
}

extern "C" void kernel_launch(void* const* d_in, const int* in_sizes, int n_in,
                              void* d_out, int out_size, void* d_ws, size_t ws_size,
                              hipStream_t stream) {
    const float* x   = (const float*)d_in[0];
    const float* emb = (const float*)d_in[1];

    float* out      = (float*)d_out;
    float* out_loss = out;
    float* out_q    = out + 1;
    float* out_perp = out + 1 + (size_t)N_ * C_;
    float* out_idx  = out + 2 + (size_t)N_ * C_;

    char* ws = (char*)d_ws;
    double*         sse     = (double*)(ws + 0);
    int*            done    = (int*)(ws + 8);
    float*          snmax_p = (float*)(ws + 56);
    float*          en      = (float*)(ws + 2112);
    float*          embT32  = (float*)(ws + 4160);
    unsigned short* fBhi    = (unsigned short*)(ws + 135232);
    unsigned short* fBlo    = (unsigned short*)(ws + 200768);

    vq_init<<<65, 512, 0, stream>>>(emb, sse, done, snmax_p, en, embT32, fBhi, fBlo);
    vq_fused<<<NBLK_, 256, 0, stream>>>(x, en, embT32, fBhi, fBlo, snmax_p,
                                        out_q, out_idx, out_loss, out_perp,
                                        sse, done);
}

// Round 8
// 196.207 us; speedup vs baseline: 1.7195x; 1.7195x over previous
//
#include <hip/hip_runtime.h>

// VQ-VAE vector quantizer — R8.
// R7 post-mortem: done-counter/threadfence/atomic-store grid-sync poisoned the
// kernel (+230 us, all pipes idle). NEVER grid-sync in-kernel on CDNA4.
// R8 = R6 shell, 3 launches, plus:
//  - rescue with coalesced code-major loop over ORIGINAL emb[c][k] layout
//    (512 coalesced 256B loads vs 8K scattered lines per rescue row);
//  - 8-MFMA full bf16x2 product (halves sound W -> ~halves flag rate);
//  - 128 rows/block, 2 row-tiles/wave, B streamed through LDS double-buffer
//    (B L2 traffic 1 GB -> 128 MB);
//  - single-block tail kernel: hist + loss + perplexity (merges 2 launches).

#define B_ 32
#define C_ 64
#define HW_ 4096
#define K_ 512
#define N_ (B_ * HW_)
#define NC_ ((long long)N_ * C_)
#define ROWS_ 128
#define NBLK_ (N_ / ROWS_)     // 1024

typedef __attribute__((ext_vector_type(8))) short short8;
typedef __attribute__((ext_vector_type(4))) float float4_t;

// ---- workspace layout (bytes) ----
// 56      float  snmax               4*max_k ||e_k||^2
// 2112    float  en[512]
// 4160    float  embT32[512*64]      exact fp32 emb, [code][c]
// 135232  ushort fBhi[512*64]        bf16 hi of (-2e), fragment-linear
// 200768  ushort fBlo[512*64]        bf16 lo of (-2e), fragment-linear
// 266304  double ssepart[1024]       -> end 274496

__device__ __forceinline__ unsigned short f2bf(float f) {
    unsigned u = __float_as_uint(f);
    u += 0x7fffu + ((u >> 16) & 1u);   // RNE
    return (unsigned short)(u >> 16);
}
__device__ __forceinline__ float bf2f(unsigned short h) {
    return __uint_as_float(((unsigned)h) << 16);
}
// LDS A-tile (bf16 frag) offset: [row-tile][k-group][row-in-tile][8 k]
__device__ __forceinline__ int offA(int r, int c) {
    return ((r >> 4) << 10) + ((c >> 3) << 7) + ((r & 15) << 3) + (c & 7);
}
__device__ __forceinline__ void merge2(float& m1, int& i1, float& m2,
                                       float om1, int oi1, float om2) {
    if (om1 < m1) { m2 = fminf(m1, om2); m1 = om1; i1 = oi1; }
    else          { m2 = fminf(m2, om1); }
}

// ---------------- prologue ----------------
__global__ __launch_bounds__(512) void vq_init(const float* __restrict__ emb,
                                               float* __restrict__ snmax_p,
                                               float* __restrict__ en,
                                               float* __restrict__ embT32,
                                               unsigned short* __restrict__ fBhi,
                                               unsigned short* __restrict__ fBlo) {
    __shared__ float smax[8];
    int k = threadIdx.x;                  // code 0..511
    if (blockIdx.x < 64) {
        int c = blockIdx.x;
        float e = emb[c * K_ + k];        // coalesced over k
        embT32[k * C_ + c] = e;
        float s = -2.0f * e;
        unsigned short hi = f2bf(s);
        unsigned short lo = f2bf(s - bf2f(hi));
        // fragment-linear: iter it=k>>4 occupies shorts [it*1024, it*1024+1024)
        int kk   = c >> 5;
        int lane = (((c & 31) >> 3) << 4) + (k & 15);
        int fb   = ((k >> 5) << 2) + (((k >> 4) & 1) << 1) + kk;
        int off  = (fb << 9) + (lane << 3) + (c & 7);
        fBhi[off] = hi;
        fBlo[off] = lo;
    } else {
        float s = 0.f;
#pragma unroll
        for (int c = 0; c < C_; ++c) {
            float e = emb[c * K_ + k];
            s += e * e;
        }
        en[k] = s;
        float m = s;
#pragma unroll
        for (int off = 32; off > 0; off >>= 1)
            m = fmaxf(m, __shfl_down(m, off, 64));
        if ((k & 63) == 0) smax[k >> 6] = m;
        __syncthreads();
        if (k == 0) {
            float mm = smax[0];
#pragma unroll
            for (int w2 = 1; w2 < 8; ++w2) mm = fmaxf(mm, smax[w2]);
            *snmax_p = 4.0f * mm;
        }
    }
}

// ---------------- main kernel ----------------
__global__ __launch_bounds__(256, 4) void vq_argmin(const float* __restrict__ x,
                                                    const float* __restrict__ emb,
                                                    const float* __restrict__ en_g,
                                                    const float* __restrict__ embT32,
                                                    const unsigned short* __restrict__ fBhi,
                                                    const unsigned short* __restrict__ fBlo,
                                                    const float* __restrict__ snmax_p,
                                                    float* __restrict__ out_q,
                                                    float* __restrict__ out_idx,
                                                    double* __restrict__ ssepart) {
    __shared__ unsigned short SBuf[8192];   // 16 KB: A-stage (hi then lo), then B dbuf
    __shared__ float sEn[K_];               // 2 KB
    __shared__ float znp[256];              // 1 KB
    __shared__ int   biarr[ROWS_];
    __shared__ int   flaglist[ROWS_];
    __shared__ float wsse[4];
    __shared__ int   nflag;

    const int t   = threadIdx.x;
    const int n0  = blockIdx.x << 7;       // *128
    const int b   = n0 >> 12;
    const int hw0 = n0 & 4095;
    const float* xbase = x + ((size_t)b << 18) + hw0;

    if (t == 0) nflag = 0;
    sEn[t]       = en_g[t];
    sEn[256 + t] = en_g[256 + t];

    // ---- stage hi (x retained in regs); thread: r = t&127, c = 2i + (t>>7) ----
    float v[32];
    float znacc = 0.f;
#pragma unroll
    for (int i = 0; i < 32; ++i) {
        int id = (i << 8) + t;
        int c = id >> 7;
        int r = id & 127;
        float val = xbase[((size_t)c << 12) + r];   // coalesced in r
        v[i] = val;
        znacc += val * val;
        SBuf[offA(r, c)] = f2bf(val);
    }
    znp[((t >> 7) << 7) + (t & 127)] = znacc;
    __syncthreads();

    const int lane = t & 63;
    const int w    = t >> 6;             // wave owns row-tiles {2w, 2w+1}
    const int ln15 = lane & 15;
    const int quad = lane >> 4;
    const float snm = *snmax_p;

    // ---- A-hi frags (32 VGPRs for 2 row-tiles) ----
    short8 ah[2][2], al[2][2];
    int abof[2];
#pragma unroll
    for (int rtl = 0; rtl < 2; ++rtl) {
        abof[rtl] = (((w << 1) + rtl) << 10) + (quad << 7) + (ln15 << 3);
        ah[rtl][0] = *(const short8*)(SBuf + abof[rtl]);
        ah[rtl][1] = *(const short8*)(SBuf + abof[rtl] + 512);
    }
    __syncthreads();

    // B chunk-0 prefetch into regs (hidden behind lo staging)
    uint4 ph = ((const uint4*)fBhi)[t];
    uint4 pl = ((const uint4*)fBlo)[t];

    // ---- stage lo into same buffer ----
#pragma unroll
    for (int i = 0; i < 32; ++i) {
        int id = (i << 8) + t;
        int c = id >> 7;
        int r = id & 127;
        float val = v[i];
        unsigned short hi = f2bf(val);
        SBuf[offA(r, c)] = f2bf(val - bf2f(hi));
    }
    __syncthreads();
#pragma unroll
    for (int rtl = 0; rtl < 2; ++rtl) {
        al[rtl][0] = *(const short8*)(SBuf + abof[rtl]);
        al[rtl][1] = *(const short8*)(SBuf + abof[rtl] + 512);
    }
    __syncthreads();   // all lo-frag reads done -> SBuf becomes B double-buffer

    // store chunk 0 into buf 0
    {
        uint4* dst = (uint4*)SBuf;       // buf d at uint4 offset d*512
        dst[t]       = ph;               // hi 4 KB
        dst[256 + t] = pl;               // lo 4 KB
    }
    __syncthreads();

    // ---- K-loop: 16 chunks x 2 iters x 16 codes; B from LDS; per-row top-2 ----
    float m1[2][4], m2[2][4];
    int   i1[2][4];
#pragma unroll
    for (int rtl = 0; rtl < 2; ++rtl)
#pragma unroll
        for (int reg = 0; reg < 4; ++reg) {
            m1[rtl][reg] = 3.4e38f; m2[rtl][reg] = 3.4e38f; i1[rtl][reg] = 0;
        }

    for (int cch = 0; cch < 16; ++cch) {
        const int d = cch & 1;
        if (cch < 15) {                   // early global loads for next chunk
            ph = ((const uint4*)fBhi)[((cch + 1) << 8) + t];
            pl = ((const uint4*)fBlo)[((cch + 1) << 8) + t];
        }
        const unsigned short* Bb = SBuf + (d << 12);
#pragma unroll
        for (int q = 0; q < 2; ++q) {
            const unsigned short* Bh = Bb + (q << 10);
            const unsigned short* Bl = Bb + 2048 + (q << 10);
            short8 bh0 = *(const short8*)(Bh + (lane << 3));       // ds_read_b128
            short8 bh1 = *(const short8*)(Bh + 512 + (lane << 3));
            short8 bl0 = *(const short8*)(Bl + (lane << 3));
            short8 bl1 = *(const short8*)(Bl + 512 + (lane << 3));
            const int it  = (cch << 1) + q;
            const float env = sEn[(it << 4) + ln15];
            const int   idx = (it << 4) + ln15;
#pragma unroll
            for (int rtl = 0; rtl < 2; ++rtl) {
                float4_t a0 = {env, env, env, env};   // fold ||e||^2 into acc
                float4_t a1 = {0.f, 0.f, 0.f, 0.f};
                a0 = __builtin_amdgcn_mfma_f32_16x16x32_bf16(al[rtl][0], bl0, a0, 0, 0, 0);
                a1 = __builtin_amdgcn_mfma_f32_16x16x32_bf16(al[rtl][1], bl1, a1, 0, 0, 0);
                a0 = __builtin_amdgcn_mfma_f32_16x16x32_bf16(al[rtl][0], bh0, a0, 0, 0, 0);
                a1 = __builtin_amdgcn_mfma_f32_16x16x32_bf16(al[rtl][1], bh1, a1, 0, 0, 0);
                a0 = __builtin_amdgcn_mfma_f32_16x16x32_bf16(ah[rtl][0], bl0, a0, 0, 0, 0);
                a1 = __builtin_amdgcn_mfma_f32_16x16x32_bf16(ah[rtl][1], bl1, a1, 0, 0, 0);
                a0 = __builtin_amdgcn_mfma_f32_16x16x32_bf16(ah[rtl][0], bh0, a0, 0, 0, 0);
                a1 = __builtin_amdgcn_mfma_f32_16x16x32_bf16(ah[rtl][1], bh1, a1, 0, 0, 0);
#pragma unroll
                for (int reg = 0; reg < 4; ++reg) {
                    float vv = a0[reg] + a1[reg];
                    if (vv < m1[rtl][reg]) {
                        m2[rtl][reg] = m1[rtl][reg]; m1[rtl][reg] = vv; i1[rtl][reg] = idx;
                    } else {
                        m2[rtl][reg] = fminf(m2[rtl][reg], vv);
                    }
                }
            }
        }
        __syncthreads();                  // all waves done reading buf d
        if (cch < 15) {
            uint4* dst = (uint4*)SBuf + ((d ^ 1) << 9);
            dst[t]       = ph;
            dst[256 + t] = pl;
        }
        __syncthreads();                  // stores visible before next chunk
    }

    // ---- 16-lane butterfly finalize + flag decision ----
#pragma unroll
    for (int rtl = 0; rtl < 2; ++rtl)
#pragma unroll
        for (int reg = 0; reg < 4; ++reg) {
            float a1v = m1[rtl][reg], a2v = m2[rtl][reg];
            int   ai  = i1[rtl][reg];
#pragma unroll
            for (int s = 1; s < 16; s <<= 1) {
                float o1 = __shfl_xor(a1v, s, 16);
                int   oi = __shfl_xor(ai, s, 16);
                float o2 = __shfl_xor(a2v, s, 16);
                merge2(a1v, ai, a2v, o1, oi, o2);
            }
            if (ln15 == 0) {
                int row = (((w << 1) + rtl) << 4) + (quad << 2) + reg;
                float znr = znp[row] + znp[128 + row];
                // sound 2x err bound: full 4-product repr + fp32 accum slack
                float S = __builtin_sqrtf(znr * snm);
                float W = 6.5e-5f * S + 3e-6f * (znr + snm) + 1e-4f;
                biarr[row] = ai;
                if (a2v > a1v + W) {      // gap > W => approx argmin == exact argmin
                    out_idx[n0 + row] = (float)ai;
                } else {
                    int pos = atomicAdd(&nflag, 1);   // LDS atomic
                    flaglist[pos] = row;
                }
            }
        }
    __syncthreads();

    // ---- exact fp32 rescue, COALESCED: k = j*64+lane over original emb[c][k] ----
    int nf = nflag;
    for (int f = w; f < nf; f += 4) {
        int r = flaglist[f];
        float zl = xbase[((size_t)lane << 12) + r];   // exact z[c=lane], L2-hot
        float dd[8];
#pragma unroll
        for (int j = 0; j < 8; ++j) dd[j] = 0.f;
        for (int c = 0; c < C_; ++c) {
            float zc = __shfl(zl, c, 64);
            const float* ep = emb + (c << 9);
#pragma unroll
            for (int j = 0; j < 8; ++j)
                dd[j] = fmaf(zc, ep[(j << 6) + lane], dd[j]);   // 256B coalesced
        }
        float znr = znp[r] + znp[128 + r];
        float best = 3.4e38f;
        int   bidx = 0;
#pragma unroll
        for (int j = 0; j < 8; ++j) {
            int k = (j << 6) + lane;
            float dist = (znr + sEn[k]) - 2.f * dd[j];   // reference eval order
            if (dist < best) { best = dist; bidx = k; }  // j asc => k asc: first-occurrence
        }
#pragma unroll
        for (int off = 32; off > 0; off >>= 1) {
            float ov = __shfl_down(best, off, 64);
            int   oi = __shfl_down(bidx, off, 64);
            if (ov < best || (ov == best && oi < bidx)) { best = ov; bidx = oi; }
        }
        if (lane == 0) {
            biarr[r] = bidx;
            out_idx[n0 + r] = (float)bidx;
        }
    }
    __syncthreads();

    // ---- phase 2 (register-based): rows {2w,2w+1}*16+ln15, c = quad*8+j (+32) ----
    float sacc = 0.f;
#pragma unroll
    for (int rtl = 0; rtl < 2; ++rtl) {
        const int myrow = (((w << 1) + rtl) << 4) + ln15;
        const int code  = biarr[myrow];
        const float* eb = embT32 + (code << 6) + (quad << 3);
        float4_t e0 = *(const float4_t*)(eb);
        float4_t e1 = *(const float4_t*)(eb + 4);
        float4_t e2 = *(const float4_t*)(eb + 32);
        float4_t e3 = *(const float4_t*)(eb + 36);
        float* qrow = out_q + ((size_t)b << 18) + hw0 + myrow;
#pragma unroll
        for (int j = 0; j < 4; ++j) {
            int c0 = (quad << 3) + j;
            int c1 = (quad << 3) + 4 + j;
            float zA = bf2f((unsigned short)ah[rtl][0][j])     + bf2f((unsigned short)al[rtl][0][j]);
            float zB = bf2f((unsigned short)ah[rtl][0][4 + j]) + bf2f((unsigned short)al[rtl][0][4 + j]);
            float dA = e0[j] - zA, dB = e1[j] - zB;
            sacc += dA * dA + dB * dB;
            qrow[(size_t)c0 << 12] = e0[j];
            qrow[(size_t)c1 << 12] = e1[j];
            float zC = bf2f((unsigned short)ah[rtl][1][j])     + bf2f((unsigned short)al[rtl][1][j]);
            float zD = bf2f((unsigned short)ah[rtl][1][4 + j]) + bf2f((unsigned short)al[rtl][1][4 + j]);
            float dC = e2[j] - zC, dD = e3[j] - zD;
            sacc += dC * dC + dD * dD;
            qrow[(size_t)(32 + c0) << 12] = e2[j];
            qrow[(size_t)(32 + c1) << 12] = e3[j];
        }
    }
#pragma unroll
    for (int off = 32; off > 0; off >>= 1)
        sacc += __shfl_down(sacc, off, 64);
    if (lane == 0) wsse[w] = sacc;
    __syncthreads();
    if (t == 0)
        ssepart[blockIdx.x] = (double)wsse[0] + (double)wsse[1]
                            + (double)wsse[2] + (double)wsse[3];
}

// ---------------- tail: histogram + loss + perplexity (1 block) ----------------
__global__ __launch_bounds__(512) void vq_tail(const float* __restrict__ out_idx,
                                               const double* __restrict__ ssepart,
                                               float* __restrict__ out_loss,
                                               float* __restrict__ out_perp) {
    __shared__ int    h[K_];
    __shared__ float  wsf[8];
    __shared__ double wsd[8];
    int t = threadIdx.x;
    h[t] = 0;
    __syncthreads();
#pragma unroll 8
    for (int i = 0; i < N_ / 512; ++i) {
        int k = (int)out_idx[(i << 9) + t];   // 2KB coalesced per iter
        atomicAdd(&h[k], 1);                  // LDS atomic
    }
    __syncthreads();
    float p = (float)h[t] / (float)N_;
    float s = p * logf(p + 1e-10f);
    double d = ssepart[t] + ssepart[512 + t];
#pragma unroll
    for (int off = 32; off > 0; off >>= 1) {
        s += __shfl_down(s, off, 64);
        d += __shfl_down(d, off, 64);
    }
    if ((t & 63) == 0) { wsf[t >> 6] = s; wsd[t >> 6] = d; }
    __syncthreads();
    if (t == 0) {
        float  S = 0.f;
        double D = 0.0;
#pragma unroll
        for (int w = 0; w < 8; ++w) { S += wsf[w]; D += wsd[w]; }
        *out_perp = expf(-S);
        *out_loss = (float)(1.25 * D / (double)NC_);
    }
}

extern "C" void kernel_launch(void* const* d_in, const int* in_sizes, int n_in,
                              void* d_out, int out_size, void* d_ws, size_t ws_size,
                              hipStream_t stream) {
    const float* x   = (const float*)d_in[0];
    const float* emb = (const float*)d_in[1];

    float* out      = (float*)d_out;
    float* out_loss = out;
    float* out_q    = out + 1;
    float* out_perp = out + 1 + (size_t)N_ * C_;
    float* out_idx  = out + 2 + (size_t)N_ * C_;

    char* ws = (char*)d_ws;
    float*          snmax_p = (float*)(ws + 56);
    float*          en      = (float*)(ws + 2112);
    float*          embT32  = (float*)(ws + 4160);
    unsigned short* fBhi    = (unsigned short*)(ws + 135232);
    unsigned short* fBlo    = (unsigned short*)(ws + 200768);
    double*         ssepart = (double*)(ws + 266304);

    vq_init<<<65, 512, 0, stream>>>(emb, snmax_p, en, embT32, fBhi, fBlo);
    vq_argmin<<<NBLK_, 256, 0, stream>>>(x, emb, en, embT32, fBhi, fBlo, snmax_p,
                                         out_q, out_idx, ssepart);
    vq_tail<<<1, 512, 0, stream>>>(out_idx, ssepart, out_loss, out_perp);
}